// Round 1
// baseline (145.458 us; speedup 1.0000x reference)
//
#include <hip/hip_runtime.h>

#define SEQ_L 4096
#define BATCH 4
#define DMODEL 512

// ---------------------------------------------------------------------------
// scores kernel: one block per output row (b, i).
//   t = time / 200; s = 100*exp(-((ti-tj)^2)^2 / 2.5e-5); causal mask; softmax.
//   Row max is exactly 100 (j==i term), masked terms underflow to exact 0 in
//   fp32 (exp(-1100)), so softmax = exp(s-100)/sum_{j<=i} exp(s-100).
// ---------------------------------------------------------------------------
__global__ __launch_bounds__(256) void scores_kernel(const float* __restrict__ tm,
                                                     float* __restrict__ out) {
    __shared__ float ts[SEQ_L];
    __shared__ float part[4];

    const int row = blockIdx.x;            // b*L + i
    const int b = row >> 12;
    const int i = row & (SEQ_L - 1);
    const float inv_tmax = 1.0f / 200.0f;

    // stage normalized times for this batch row into LDS (vectorized)
    const float4* tb4 = (const float4*)(tm + b * SEQ_L);
    float4* ts4 = (float4*)ts;
    for (int j = threadIdx.x; j < SEQ_L / 4; j += 256) {
        float4 v = tb4[j];
        v.x *= inv_tmax; v.y *= inv_tmax; v.z *= inv_tmax; v.w *= inv_tmax;
        ts4[j] = v;
    }
    __syncthreads();

    const float ti = ts[i];

    // pass 1: denominator over j <= i
    float sum = 0.0f;
    for (int j = threadIdx.x; j <= i; j += 256) {
        float diff = ti - ts[j];
        float d2 = diff * diff;
        float s = 100.0f * expf(-(d2 * d2) * 40000.0f);   // sigma^2 * exp(-d^2/lambd^2)
        sum += expf(s - 100.0f);
    }
    // wave reduce (64-lane) then cross-wave via LDS
    #pragma unroll
    for (int off = 32; off > 0; off >>= 1) sum += __shfl_down(sum, off, 64);
    if ((threadIdx.x & 63) == 0) part[threadIdx.x >> 6] = sum;
    __syncthreads();
    const float inv_denom = 1.0f / (part[0] + part[1] + part[2] + part[3]);

    // pass 2: recompute + vectorized store of the full row (zeros for j > i)
    float4* out4 = (float4*)(out + (size_t)row * SEQ_L);
    for (int j4 = threadIdx.x; j4 < SEQ_L / 4; j4 += 256) {
        const int j = j4 * 4;
        float4 v;
        float* vp = &v.x;
        #pragma unroll
        for (int c = 0; c < 4; ++c) {
            const int jj = j + c;
            float r = 0.0f;
            if (jj <= i) {
                float diff = ti - ts[jj];
                float d2 = diff * diff;
                float s = 100.0f * expf(-(d2 * d2) * 40000.0f);
                r = expf(s - 100.0f) * inv_denom;
            }
            vp[c] = r;
        }
        out4[j4] = v;
    }
}

// ---------------------------------------------------------------------------
// embedding kernel: [B, L, 2D]; first D = sinusoidal temporal enc, last D =
// emb_table[event_type] * sqrt(D). Grid-stride elementwise.
// ---------------------------------------------------------------------------
__global__ __launch_bounds__(256) void emb_kernel(const int* __restrict__ et,
                                                  const float* __restrict__ tm,
                                                  const float* __restrict__ tab,
                                                  float* __restrict__ out) {
    const int total = BATCH * SEQ_L * 2 * DMODEL;          // 16,777,216
    const int stride = gridDim.x * blockDim.x;
    for (int idx = blockIdx.x * blockDim.x + threadIdx.x; idx < total; idx += stride) {
        const int k = idx & (2 * DMODEL - 1);
        const int bl = idx >> 10;                          // b*L + l
        float r;
        if (k < DMODEL) {
            // pos_vec = 10000^(2*(k//2)/D); even -> sin, odd -> cos
            float ex = (float)(k & ~1) * (1.0f / (float)DMODEL);
            float pos = powf(10000.0f, ex);
            float temp = tm[bl] / pos;
            r = (k & 1) ? cosf(temp) : sinf(temp);
        } else {
            r = tab[et[bl] * DMODEL + (k - DMODEL)] * 22.627416997969522f; // sqrt(512)
        }
        out[idx] = r;
    }
}

extern "C" void kernel_launch(void* const* d_in, const int* in_sizes, int n_in,
                              void* d_out, int out_size, void* d_ws, size_t ws_size,
                              hipStream_t stream) {
    const int*   event_type = (const int*)d_in[0];
    const float* event_time = (const float*)d_in[1];
    const float* emb_table  = (const float*)d_in[2];

    float* scores = (float*)d_out;
    float* emb    = scores + (size_t)BATCH * SEQ_L * SEQ_L;

    scores_kernel<<<BATCH * SEQ_L, 256, 0, stream>>>(event_time, scores);
    emb_kernel<<<4096, 256, 0, stream>>>(event_type, event_time, emb_table, emb);
}

// Round 2
// 67.466 us; speedup vs baseline: 2.1560x; 2.1560x over previous
//
#include <hip/hip_runtime.h>

#define SEQ_L 4096
#define BATCH 4
#define DMODEL 512
#define ROWS_PER_BLOCK 4
#define CUT 0.055f   // normalized-time gap beyond which exp(s-100) < 5e-14

// ---------------------------------------------------------------------------
// scores: one block = 4 consecutive rows of one batch; one WAVE per row.
// Row math: t = time/200; z = ((ti-tj)^2)^2 * 40000; s = 100*exp(-z);
// softmax row max is exactly 100 (diagonal), masked terms are exact 0,
// and s < 100-CUT-margin terms underflow below 5e-14 -> store exact zeros.
// Sorted times => non-negligible columns are the contiguous band [jlo, i].
// ---------------------------------------------------------------------------
__global__ __launch_bounds__(256) void scores_kernel(const float* __restrict__ tm,
                                                     float* __restrict__ out) {
    __shared__ float ts[SEQ_L];

    const int b  = blockIdx.x / (SEQ_L / ROWS_PER_BLOCK);
    const int i0 = (blockIdx.x % (SEQ_L / ROWS_PER_BLOCK)) * ROWS_PER_BLOCK;

    // stage normalized times for this batch into LDS (match ref's /200.0 div)
    const float4* tb4 = (const float4*)(tm + b * SEQ_L);
    float4* ts4 = (float4*)ts;
    for (int j = threadIdx.x; j < SEQ_L / 4; j += 256) {
        float4 v = tb4[j];
        v.x /= 200.0f; v.y /= 200.0f; v.z /= 200.0f; v.w /= 200.0f;
        ts4[j] = v;
    }
    __syncthreads();

    const int wave = threadIdx.x >> 6;
    const int lane = threadIdx.x & 63;
    const int i = i0 + wave;
    const float ti = ts[i];
    const float tcut = ti - CUT;

    // lower_bound for first j with ts[j] >= ti - CUT (uniform across wave)
    int lo = 0, hi = i;
    while (lo < hi) {
        int mid = (lo + hi) >> 1;
        if (ts[mid] < tcut) lo = mid + 1; else hi = mid;
    }
    const int jlo = lo;

    // denominator over the band (dropped terms < 5e-14 each, sum >= 1)
    float sum = 0.0f;
    for (int j = jlo + lane; j <= i; j += 64) {
        float d = ti - ts[j];
        float d2 = d * d;
        float s = 100.0f * expf(-(d2 * d2) * 40000.0f);
        sum += expf(s - 100.0f);
    }
    #pragma unroll
    for (int off = 1; off < 64; off <<= 1) sum += __shfl_xor(sum, off, 64);
    const float inv_denom = 1.0f / sum;

    // write full row: zeros outside [jlo, i], computed values inside
    float4* out4 = (float4*)(out + ((size_t)(b * SEQ_L + i)) * SEQ_L);
    for (int c = lane; c < SEQ_L / 4; c += 64) {
        const int j = c * 4;
        float4 v = make_float4(0.0f, 0.0f, 0.0f, 0.0f);
        if (j + 3 >= jlo && j <= i) {           // chunk intersects band
            float* vp = &v.x;
            #pragma unroll
            for (int q = 0; q < 4; ++q) {
                const int jj = j + q;
                if (jj >= jlo && jj <= i) {
                    float d = ti - ts[jj];
                    float d2 = d * d;
                    float s = 100.0f * expf(-(d2 * d2) * 40000.0f);
                    vp[q] = expf(s - 100.0f) * inv_denom;
                }
            }
        }
        out4[c] = v;
    }
}

// ---------------------------------------------------------------------------
// embedding: block row-loops over (b,l); waves 0-1 (threads <128) do the
// sinusoidal half (inv_pos hoisted per-thread via exp2f, constant across
// rows), waves 2-3 load the type-embedding row * sqrt(512). Unified float4
// store at column 4*tid.
// ---------------------------------------------------------------------------
__global__ __launch_bounds__(256) void emb_kernel(const int* __restrict__ et,
                                                  const float* __restrict__ tm,
                                                  const float* __restrict__ tab,
                                                  float* __restrict__ out) {
    const int t = threadIdx.x;
    const bool temporal = t < 128;

    // inv_pos = 10000^(-2*(k//2)/512) = exp2(-(k//2)/256 * log2(10000))
    float ipA = 0.0f, ipB = 0.0f;
    if (temporal) {
        const float c = -13.287712379549449f / 256.0f;   // -log2(10000)/256
        ipA = exp2f(c * (float)(2 * t));
        ipB = exp2f(c * (float)(2 * t + 1));
    }
    const int ecol = (t - 128) * 4;   // valid for !temporal

    for (int bl = blockIdx.x; bl < BATCH * SEQ_L; bl += gridDim.x) {
        float4 v;
        if (temporal) {
            const float time = tm[bl];
            const float a = time * ipA;
            const float bph = time * ipB;
            v.x = sinf(a);  v.y = cosf(a);
            v.z = sinf(bph); v.w = cosf(bph);
        } else {
            const float4 e = *(const float4*)(tab + et[bl] * DMODEL + ecol);
            const float sc = 22.627416997969522f;        // sqrt(512)
            v.x = e.x * sc; v.y = e.y * sc; v.z = e.z * sc; v.w = e.w * sc;
        }
        ((float4*)(out + (size_t)bl * 2 * DMODEL))[t] = v;
    }
}

extern "C" void kernel_launch(void* const* d_in, const int* in_sizes, int n_in,
                              void* d_out, int out_size, void* d_ws, size_t ws_size,
                              hipStream_t stream) {
    const int*   event_type = (const int*)d_in[0];
    const float* event_time = (const float*)d_in[1];
    const float* emb_table  = (const float*)d_in[2];

    float* scores = (float*)d_out;
    float* emb    = scores + (size_t)BATCH * SEQ_L * SEQ_L;

    scores_kernel<<<BATCH * SEQ_L / ROWS_PER_BLOCK, 256, 0, stream>>>(event_time, scores);
    emb_kernel<<<2048, 256, 0, stream>>>(event_type, event_time, emb_table, emb);
}

// Round 3
// 65.337 us; speedup vs baseline: 2.2263x; 1.0326x over previous
//
#include <hip/hip_runtime.h>

#define SEQ_L 4096
#define BATCH 4
#define DMODEL 512
#define CUT 0.055f            // gap beyond which exp(s-100) < 5e-14
#define RPB 16                // score rows per block (4 waves x 4 rows)
#define SCORE_BLOCKS (BATCH * SEQ_L / RPB)   // 1024
#define EMB_BLOCKS 512
#define EMB_RPB (BATCH * SEQ_L / EMB_BLOCKS) // 32

// Fused kernel. Blocks [0, SCORE_BLOCKS) compute softmax score rows;
// blocks [SCORE_BLOCKS, SCORE_BLOCKS+EMB_BLOCKS) compute the embedding.
// Scores: t = time/200; s = 100*exp(-((ti-tj)^2)^2*40000); causal softmax.
// Row max is exactly 100 (diagonal), masked/far terms are exact fp32 zeros,
// sorted times => non-negligible columns form contiguous band [jlo, i].
__global__ __launch_bounds__(256) void fused_kernel(const int* __restrict__ et,
                                                    const float* __restrict__ tm,
                                                    const float* __restrict__ tab,
                                                    float* __restrict__ scores,
                                                    float* __restrict__ emb) {
    if (blockIdx.x < SCORE_BLOCKS) {
        // ---------------- scores path ----------------
        __shared__ float ts[SEQ_L];
        const int b  = blockIdx.x / (SEQ_L / RPB);
        const int i0 = (blockIdx.x % (SEQ_L / RPB)) * RPB;

        const float4* tb4 = (const float4*)(tm + b * SEQ_L);
        float4* ts4 = (float4*)ts;
        const float inv_tmax = 1.0f / 200.0f;
        #pragma unroll
        for (int q = 0; q < 4; ++q) {
            int j = threadIdx.x + q * 256;
            float4 v = tb4[j];
            v.x *= inv_tmax; v.y *= inv_tmax; v.z *= inv_tmax; v.w *= inv_tmax;
            ts4[j] = v;
        }
        __syncthreads();

        const int wave = threadIdx.x >> 6;
        const int lane = threadIdx.x & 63;
        const int ibase = i0 + wave * 4;

        // binary search once per wave (first row), then walk forward
        int jlo;
        {
            const float tc = ts[ibase] - CUT;
            int lo = 0, hi = ibase;
            while (lo < hi) {
                int mid = (lo + hi) >> 1;
                if (ts[mid] < tc) lo = mid + 1; else hi = mid;
            }
            jlo = lo;
        }

        for (int r = 0; r < 4; ++r) {
            const int i = ibase + r;
            const float ti = ts[i];
            const float tc = ti - CUT;
            while (ts[jlo] < tc) ++jlo;     // monotone advance (uniform)

            float sum = 0.0f;
            for (int j = jlo + lane; j <= i; j += 64) {
                float d = ti - ts[j];
                float d2 = d * d;
                float s = 100.0f * __expf(-(d2 * d2) * 40000.0f);
                sum += __expf(s - 100.0f);
            }
            #pragma unroll
            for (int off = 1; off < 64; off <<= 1) sum += __shfl_xor(sum, off, 64);
            const float inv_denom = 1.0f / sum;

            float4* out4 = (float4*)(scores + ((size_t)(b * SEQ_L + i)) * SEQ_L);
            for (int c = lane; c < SEQ_L / 4; c += 64) {
                const int j = c * 4;
                float4 v = make_float4(0.0f, 0.0f, 0.0f, 0.0f);
                if (j + 3 >= jlo && j <= i) {
                    float* vp = &v.x;
                    #pragma unroll
                    for (int q = 0; q < 4; ++q) {
                        const int jj = j + q;
                        if (jj >= jlo && jj <= i) {
                            float d = ti - ts[jj];
                            float d2 = d * d;
                            float s = 100.0f * __expf(-(d2 * d2) * 40000.0f);
                            vp[q] = __expf(s - 100.0f) * inv_denom;
                        }
                    }
                }
                out4[c] = v;
            }
        }
    } else {
        // ---------------- embedding path ----------------
        const int t = threadIdx.x;
        const bool temporal = t < 128;

        float ipA = 0.0f, ipB = 0.0f;
        if (temporal) {
            const float c = -13.287712379549449f / 256.0f;   // -log2(10000)/256
            ipA = exp2f(c * (float)(2 * t));
            ipB = exp2f(c * (float)(2 * t + 1));
        }
        const int ecol = (t - 128) * 4;

        const int bl0 = (blockIdx.x - SCORE_BLOCKS) * EMB_RPB;
        for (int r = 0; r < EMB_RPB; ++r) {
            const int bl = bl0 + r;
            float4 v;
            if (temporal) {
                const float time = tm[bl];
                const float a = time * ipA;
                const float bp = time * ipB;
                v.x = __sinf(a);  v.y = __cosf(a);
                v.z = __sinf(bp); v.w = __cosf(bp);
            } else {
                const float4 e = *(const float4*)(tab + et[bl] * DMODEL + ecol);
                const float sc = 22.627416997969522f;        // sqrt(512)
                v.x = e.x * sc; v.y = e.y * sc; v.z = e.z * sc; v.w = e.w * sc;
            }
            ((float4*)(emb + (size_t)bl * 2 * DMODEL))[t] = v;
        }
    }
}

extern "C" void kernel_launch(void* const* d_in, const int* in_sizes, int n_in,
                              void* d_out, int out_size, void* d_ws, size_t ws_size,
                              hipStream_t stream) {
    const int*   event_type = (const int*)d_in[0];
    const float* event_time = (const float*)d_in[1];
    const float* emb_table  = (const float*)d_in[2];

    float* scores = (float*)d_out;
    float* emb    = scores + (size_t)BATCH * SEQ_L * SEQ_L;

    fused_kernel<<<SCORE_BLOCKS + EMB_BLOCKS, 256, 0, stream>>>(
        event_type, event_time, emb_table, scores, emb);
}